// Round 3
// baseline (541.177 us; speedup 1.0000x reference)
//
#include <hip/hip_runtime.h>
#include <math.h>

constexpr int H = 1024;
constexpr int V = 50257;
constexpr int L = 64;

constexpr int NB   = 768;   // blocks = 3/CU on 256 CUs (co-residency guaranteed)
constexpr int NT   = 256;   // threads/block (4 waves)
constexpr int NW   = NB * 4; // 3072 waves
constexpr int NGRP = 48;    // barrier groups of 16 blocks

// Barrier region (uints), zeroed by a memset node each call:
//  leafcnt[slot][g] = slot*64 + g     slots 0..3, g 0..47
//  root[slot]       = 256 + slot*16
//  rel[g]           = 320 + g*16      (monotone: value = last released slot+1)
constexpr int BAR_UINTS = 1088;

// Float offsets into ws (after barrier region)
constexpr int OFF_WE   = BAR_UINTS;        // 64  attn logits, emb half
constexpr int OFF_WH   = OFF_WE + 64;      // 64  attn logits, hid half (incl. bias later)
constexpr int OFF_GH   = OFF_WH + 64;      // 3072 gh = w_hh@h0 + b_hh
constexpr int OFF_CP   = OFF_GH + 3 * H;   // 1024 comb emb-half partial
constexpr int OFF_X    = OFF_CP + H;       // 1024 x = relu(comb)
constexpr int OFF_PAIR = OFF_X + H;        // 2*NB (m,s) partials
constexpr int OFF_LOG  = OFF_PAIR + 2 * NB; // V logits

__device__ __forceinline__ float wsum(float v) {
#pragma unroll
    for (int off = 32; off > 0; off >>= 1) v += __shfl_xor(v, off);
    return v;
}

__device__ __forceinline__ float dot1024(const float* __restrict__ w,
                                         const float* __restrict__ v_lds,
                                         int lane) {
    const float4* w4 = reinterpret_cast<const float4*>(w);
    const float4* v4 = reinterpret_cast<const float4*>(v_lds);
    float acc = 0.f;
#pragma unroll
    for (int it = 0; it < 4; ++it) {
        float4 a = w4[lane + it * 64];
        float4 b = v4[lane + it * 64];
        acc += a.x * b.x + a.y * b.y + a.z * b.z + a.w * b.w;
    }
    return acc;
}

__device__ __forceinline__ void msmerge(float& m, float& s, float m2, float s2) {
    const float M = fmaxf(m, m2);
    s = s * expf(m - M) + s2 * expf(m2 - M);
    m = M;
}

__device__ __forceinline__ unsigned aload(unsigned* p) {
    return __hip_atomic_load(p, __ATOMIC_RELAXED, __HIP_MEMORY_SCOPE_AGENT);
}

// Two-level grid barrier. All NB blocks must be co-resident.
__device__ __forceinline__ void gbar(unsigned* bar, int slot) {
    __threadfence();   // release: flush this thread's stores to agent scope
    __syncthreads();
    if (threadIdx.x == 0) {
        const int b = blockIdx.x, g = b >> 4;
        unsigned* leafcnt = bar + slot * 64 + g;
        unsigned* root    = bar + 256 + slot * 16;
        unsigned* rel     = bar + 320 + g * 16;
        __hip_atomic_fetch_add(leafcnt, 1u, __ATOMIC_ACQ_REL, __HIP_MEMORY_SCOPE_AGENT);
        if ((b & 15) == 0) {  // group master
            while (aload(leafcnt) < 16u) __builtin_amdgcn_s_sleep(1);
            __hip_atomic_fetch_add(root, 1u, __ATOMIC_ACQ_REL, __HIP_MEMORY_SCOPE_AGENT);
            while (aload(root) < (unsigned)NGRP) __builtin_amdgcn_s_sleep(2);
            __hip_atomic_store(rel, (unsigned)(slot + 1), __ATOMIC_RELEASE,
                               __HIP_MEMORY_SCOPE_AGENT);
        } else {
            while (aload(rel) < (unsigned)(slot + 1)) __builtin_amdgcn_s_sleep(2);
        }
    }
    __syncthreads();
    __threadfence();   // acquire: invalidate stale local-L2 lines
}

__global__ __launch_bounds__(NT, 3) void mega(
        const long long* __restrict__ idx_p,
        const float* __restrict__ hid,
        const float* __restrict__ enc,
        const float* __restrict__ emb,
        const float* __restrict__ attn_W,
        const float* __restrict__ attn_b,
        const float* __restrict__ comb_W,
        const float* __restrict__ comb_b,
        const float* __restrict__ w_ih,
        const float* __restrict__ w_hh,
        const float* __restrict__ b_ih,
        const float* __restrict__ b_hh,
        const float* __restrict__ out_W,
        const float* __restrict__ out_b,
        float* __restrict__ ws,
        float* __restrict__ out) {
    __shared__ __align__(16) float lds_a[1024];  // hid -> x -> h_new
    __shared__ __align__(16) float lds_b[1024];  // emb_row -> attn_applied
    __shared__ float lds_c[64];                  // logits/wls, reduce slots

    unsigned* bar = reinterpret_cast<unsigned*>(ws);
    const int tid  = threadIdx.x;
    const int lane = tid & 63, wid = tid >> 6;
    const int b    = blockIdx.x;
    const int wgid = b * 4 + wid;                // 0..3071
    const int idx  = (int)idx_p[0];

    // ================= S1: gh GEMV + comb-emb-half + attn logit halves =====
    for (int i = tid; i < H; i += NT) {
        lds_a[i] = hid[i];
        lds_b[i] = emb[(size_t)idx * H + i];
    }
    __syncthreads();
    {   // gh row per wave (exactly NW == 3*H waves)
        const int r = wgid;
        float acc = dot1024(w_hh + (size_t)r * H, lds_a, lane);
        acc = wsum(acc);
        if (lane == 0) ws[OFF_GH + r] = acc + b_hh[r];
    }
    for (int u = wgid; u < H + 2 * L; u += NW) {  // <=1 iter per wave
        if (u < H) {            // comb emb-half partial (no bias)
            float acc = wsum(dot1024(comb_W + (size_t)u * (2 * H), lds_b, lane));
            if (lane == 0) ws[OFF_CP + u] = acc;
        } else if (u < H + L) { // attn logit, emb half
            const int l = u - H;
            float acc = wsum(dot1024(attn_W + (size_t)l * (2 * H), lds_b, lane));
            if (lane == 0) ws[OFF_WE + l] = acc;
        } else {                // attn logit, hid half
            const int l = u - H - L;
            float acc = wsum(dot1024(attn_W + (size_t)l * (2 * H) + H, lds_a, lane));
            if (lane == 0) ws[OFF_WH + l] = acc;
        }
    }
    gbar(bar, 0);

    // ================= S2: softmax + attn_applied + comb-attn-half -> x ====
    if (b < 256) {
        if (tid < L) lds_c[tid] = ws[OFF_WE + tid] + ws[OFF_WH + tid] + attn_b[tid];
        __syncthreads();
        float m = -INFINITY, s = 0.f;
        if (tid < L) {
            for (int i = 0; i < L; ++i) m = fmaxf(m, lds_c[i]);
            for (int i = 0; i < L; ++i) s += expf(lds_c[i] - m);
        }
        __syncthreads();
        if (tid < L) lds_c[tid] = expf(lds_c[tid] - m) / s;
        __syncthreads();
        if (b == 0 && tid < L) out[V + H + tid] = lds_c[tid];
        // attn_applied: thread owns float4 column chunk tid
        const float4* e4 = reinterpret_cast<const float4*>(enc);
        float4 a4 = {0.f, 0.f, 0.f, 0.f};
#pragma unroll 8
        for (int l = 0; l < L; ++l) {
            const float w = lds_c[l];
            const float4 v = e4[l * 256 + tid];
            a4.x += w * v.x; a4.y += w * v.y; a4.z += w * v.z; a4.w += w * v.w;
        }
        reinterpret_cast<float4*>(lds_b)[tid] = a4;  // overwrite emb (done with it)
        __syncthreads();
        // comb second half: row = b*4 + wid  (256 blocks x 4 waves = 1024 rows)
        const int r = b * 4 + wid;
        float acc = wsum(dot1024(comb_W + (size_t)r * (2 * H) + H, lds_b, lane));
        if (lane == 0)
            ws[OFF_X + r] = fmaxf(acc + ws[OFF_CP + r] + comb_b[r], 0.f);
    }
    gbar(bar, 1);

    // ================= S3: gi (3 rows per wave) + gates -> h_new ===========
    if (b < 256) {  // waves 0..1023, t = wgid
        for (int i = tid; i < H; i += NT) lds_a[i] = ws[OFF_X + i];
        __syncthreads();
        const int t = wgid;
        float g0 = wsum(dot1024(w_ih + (size_t)t * H, lds_a, lane));
        float g1 = wsum(dot1024(w_ih + (size_t)(H + t) * H, lds_a, lane));
        float g2 = wsum(dot1024(w_ih + (size_t)(2 * H + t) * H, lds_a, lane));
        if (lane == 0) {
            const float ir = g0 + b_ih[t];
            const float iz = g1 + b_ih[H + t];
            const float in_ = g2 + b_ih[2 * H + t];
            const float hr = ws[OFF_GH + t];
            const float hz = ws[OFF_GH + H + t];
            const float hn = ws[OFF_GH + 2 * H + t];
            const float r = 1.f / (1.f + expf(-(ir + hr)));
            const float z = 1.f / (1.f + expf(-(iz + hz)));
            const float n = tanhf(in_ + r * hn);
            out[V + t] = (1.f - z) * n + z * hid[t];
        }
    }
    gbar(bar, 2);

    // ================= S4: out-proj GEMV (grid-stride rows) + partials =====
    for (int i = tid; i < H; i += NT) lds_a[i] = out[V + i];  // h_new
    __syncthreads();
    float pm = -INFINITY, ps = 0.f;
    for (int r = wgid; r < V; r += NW) {
        float acc = wsum(dot1024(out_W + (size_t)r * H, lds_a, lane));
        const float logit = acc + out_b[r];
        if (lane == 0) ws[OFF_LOG + r] = logit;
        msmerge(pm, ps, logit, 1.f);
    }
    if (lane == 0) { lds_c[wid] = pm; lds_c[4 + wid] = ps; }
    __syncthreads();
    if (tid == 0) {
        float m = lds_c[0], s = lds_c[4];
        for (int i = 1; i < 4; ++i) msmerge(m, s, lds_c[i], lds_c[4 + i]);
        ws[OFF_PAIR + 2 * b] = m;
        ws[OFF_PAIR + 2 * b + 1] = s;
    }
    gbar(bar, 3);

    // ================= S5: global LSE (redundant) + final write ============
    float m = -INFINITY, s = 0.f;
    for (int i = tid; i < NB; i += NT)
        msmerge(m, s, ws[OFF_PAIR + 2 * i], ws[OFF_PAIR + 2 * i + 1]);
#pragma unroll
    for (int off = 32; off > 0; off >>= 1) {
        const float mo = __shfl_xor(m, off);
        const float so = __shfl_xor(s, off);
        msmerge(m, s, mo, so);
    }
    if (lane == 0) { lds_c[wid] = m; lds_c[4 + wid] = s; }
    __syncthreads();
    if (tid == 0) {
        float M = lds_c[0], S = lds_c[4];
        for (int i = 1; i < 4; ++i) msmerge(M, S, lds_c[i], lds_c[4 + i]);
        lds_c[8] = M;
        lds_c[9] = logf(S);
    }
    __syncthreads();
    const float MM = lds_c[8], LS = lds_c[9];
    const int i = b * NT + tid;
    if (i < V) out[i] = ws[OFF_LOG + i] - MM - LS;
}

extern "C" void kernel_launch(void* const* d_in, const int* in_sizes, int n_in,
                              void* d_out, int out_size, void* d_ws, size_t ws_size,
                              hipStream_t stream) {
    const long long* idx  = (const long long*)d_in[0];
    const float* hid    = (const float*)d_in[1];
    const float* enc    = (const float*)d_in[2];
    const float* emb    = (const float*)d_in[3];
    const float* attn_W = (const float*)d_in[4];
    const float* attn_b = (const float*)d_in[5];
    const float* comb_W = (const float*)d_in[6];
    const float* comb_b = (const float*)d_in[7];
    const float* w_ih   = (const float*)d_in[8];
    const float* w_hh   = (const float*)d_in[9];
    const float* b_ih   = (const float*)d_in[10];
    const float* b_hh   = (const float*)d_in[11];
    const float* out_W  = (const float*)d_in[12];
    const float* out_b  = (const float*)d_in[13];
    float* out = (float*)d_out;
    float* ws  = (float*)d_ws;

    hipMemsetAsync(d_ws, 0, BAR_UINTS * sizeof(unsigned), stream);
    mega<<<NB, NT, 0, stream>>>(idx, hid, enc, emb, attn_W, attn_b,
                                comb_W, comb_b, w_ih, w_hh, b_ih, b_hh,
                                out_W, out_b, ws, out);
}

// Round 4
// 81.145 us; speedup vs baseline: 6.6692x; 6.6692x over previous
//
#include <hip/hip_runtime.h>
#include <math.h>

constexpr int H = 1024;
constexpr int V = 50257;
constexpr int L = 64;

constexpr int NB   = 1024;            // 4 blocks/CU on 256 CUs
constexpr int NT   = 256;             // 4 waves/block
constexpr int NW   = NB * 4;          // 4096 waves
constexpr int NGRP = NB / 16;         // 64 barrier groups of 16 blocks
constexpr int RPB  = (V + NB - 1) / NB; // 50 out-proj rows per block

// ---- barrier region (uints, 64B-strided counters, zeroed per call) --------
constexpr int BAR_LEAF  = 0;                     // (slot*NGRP+g)*16
constexpr int BAR_ROOT  = 4 * NGRP * 16;         // + slot*16
constexpr int BAR_REL   = BAR_ROOT + 4 * 16;     // + g*16
constexpr int BAR_UINTS = BAR_REL + NGRP * 16;

// ---- ws float offsets ------------------------------------------------------
constexpr int OFF_WE   = BAR_UINTS;        // 64   attn logits, emb half
constexpr int OFF_WH   = OFF_WE + 64;      // 64   attn logits, hid half
constexpr int OFF_GH   = OFF_WH + 64;      // 3072 gh = w_hh@h0 + b_hh
constexpr int OFF_CP   = OFF_GH + 3 * H;   // 1024 comb emb-half partial
constexpr int OFF_X    = OFF_CP + H;       // 1024 x = relu(comb)
constexpr int OFF_HN   = OFF_X + H;        // 1024 h_new (device-coherent copy)
constexpr int OFF_PAIR = OFF_HN + H;       // 2*NB (m,s) partials

// Relaxed agent-scope (cache-bypassing, cross-XCD coherent) scalar access.
__device__ __forceinline__ void gput(float* p, float v) {
    __hip_atomic_store(p, v, __ATOMIC_RELAXED, __HIP_MEMORY_SCOPE_AGENT);
}
__device__ __forceinline__ float gget(const float* p) {
    return __hip_atomic_load(p, __ATOMIC_RELAXED, __HIP_MEMORY_SCOPE_AGENT);
}
__device__ __forceinline__ unsigned uget(const unsigned* p) {
    return __hip_atomic_load(p, __ATOMIC_RELAXED, __HIP_MEMORY_SCOPE_AGENT);
}

__device__ __forceinline__ float wsum(float v) {
#pragma unroll
    for (int off = 32; off > 0; off >>= 1) v += __shfl_xor(v, off);
    return v;
}
__device__ __forceinline__ float wmax(float v) {
#pragma unroll
    for (int off = 32; off > 0; off >>= 1) v = fmaxf(v, __shfl_xor(v, off));
    return v;
}

__device__ __forceinline__ float dot1024(const float* __restrict__ w,
                                         const float* __restrict__ v_lds,
                                         int lane) {
    const float4* w4 = reinterpret_cast<const float4*>(w);
    const float4* v4 = reinterpret_cast<const float4*>(v_lds);
    float acc = 0.f;
#pragma unroll
    for (int it = 0; it < 4; ++it) {
        float4 a = w4[lane + it * 64];
        float4 b = v4[lane + it * 64];
        acc += a.x * b.x + a.y * b.y + a.z * b.z + a.w * b.w;
    }
    return acc;
}

__device__ __forceinline__ void msmerge(float& m, float& s, float m2, float s2) {
    const float M = fmaxf(m, m2);
    s = s * expf(m - M) + s2 * expf(m2 - M);
    m = M;
}

// Two-level grid barrier, RELAXED atomics only (no L2 writeback/invalidate).
// Data ordering: __syncthreads() drains each wave's vmcnt (sc1 stores have
// reached the coherence point); consumers use sc1 loads (gget).
__device__ __forceinline__ void gbar(unsigned* bar, int slot) {
    __syncthreads();
    if (threadIdx.x == 0) {
        const int b = blockIdx.x, g = b >> 4;
        unsigned* leaf = bar + (slot * NGRP + g) * 16;
        unsigned* root = bar + BAR_ROOT + slot * 16;
        unsigned* rel  = bar + BAR_REL + g * 16;
        __hip_atomic_fetch_add(leaf, 1u, __ATOMIC_RELAXED, __HIP_MEMORY_SCOPE_AGENT);
        if ((b & 15) == 0) {
            while (uget(leaf) < 16u) __builtin_amdgcn_s_sleep(1);
            __hip_atomic_fetch_add(root, 1u, __ATOMIC_RELAXED, __HIP_MEMORY_SCOPE_AGENT);
            while (uget(root) < (unsigned)NGRP) __builtin_amdgcn_s_sleep(2);
            __hip_atomic_store(rel, (unsigned)(slot + 1), __ATOMIC_RELAXED,
                               __HIP_MEMORY_SCOPE_AGENT);
        } else {
            while (uget(rel) < (unsigned)(slot + 1)) __builtin_amdgcn_s_sleep(2);
        }
    }
    __syncthreads();
}

__global__ __launch_bounds__(NT, 4) void mega(
        const long long* __restrict__ idx_p,
        const float* __restrict__ hid,
        const float* __restrict__ enc,
        const float* __restrict__ emb,
        const float* __restrict__ attn_W,
        const float* __restrict__ attn_b,
        const float* __restrict__ comb_W,
        const float* __restrict__ comb_b,
        const float* __restrict__ w_ih,
        const float* __restrict__ w_hh,
        const float* __restrict__ b_ih,
        const float* __restrict__ b_hh,
        const float* __restrict__ out_W,
        const float* __restrict__ out_b,
        float* __restrict__ ws,
        float* __restrict__ out) {
    __shared__ __align__(16) float lds_a[H];    // hid -> x -> h_new
    __shared__ __align__(16) float lds_b[H];    // emb_row -> attn_applied
    __shared__ float lds_c[64];                 // wls / reduce slots
    __shared__ float lds_log[64];               // this block's out-proj logits

    unsigned* bar = reinterpret_cast<unsigned*>(ws);
    const int tid  = threadIdx.x;
    const int lane = tid & 63, wid = tid >> 6;
    const int b    = blockIdx.x;
    const int w    = b * 4 + wid;              // global wave id, 0..4095
    const int idx  = (int)idx_p[0];

    // ===== S1: gh GEMV + comb-emb-half + attn-logit halves =================
    for (int i = tid; i < H; i += NT) {
        lds_a[i] = hid[i];
        lds_b[i] = emb[(size_t)idx * H + i];
    }
    __syncthreads();
    if (w < 3 * H) {                 // gh row
        float acc = wsum(dot1024(w_hh + (size_t)w * H, lds_a, lane));
        if (lane == 0) gput(ws + OFF_GH + w, acc + b_hh[w]);
    } else {                         // comb emb-half partial
        const int r = w - 3 * H;
        float acc = wsum(dot1024(comb_W + (size_t)r * (2 * H), lds_b, lane));
        if (lane == 0) gput(ws + OFF_CP + r, acc);
    }
    if (w < 2 * L) {                 // attn logit halves (waves 0..127 double up)
        if (w < L) {
            float acc = wsum(dot1024(attn_W + (size_t)w * (2 * H), lds_b, lane));
            if (lane == 0) gput(ws + OFF_WE + w, acc);
        } else {
            const int l = w - L;
            float acc = wsum(dot1024(attn_W + (size_t)l * (2 * H) + H, lds_a, lane));
            if (lane == 0) gput(ws + OFF_WH + l, acc);
        }
    }
    gbar(bar, 0);

    // ===== S2: softmax + attn_applied + comb-attn-half -> x ================
    if (b < 256) {
        if (wid == 0) {  // wave 0: all of softmax (L == 64 == wave size)
            const float lg = gget(ws + OFF_WE + lane) + gget(ws + OFF_WH + lane)
                           + attn_b[lane];
            const float m = wmax(lg);
            const float e = expf(lg - m);
            const float s = wsum(e);
            const float wl = e / s;
            lds_c[lane] = wl;
            if (b == 0) out[V + H + lane] = wl;
        }
        __syncthreads();
        const float4* e4 = reinterpret_cast<const float4*>(enc);
        float4 a4 = {0.f, 0.f, 0.f, 0.f};
#pragma unroll 8
        for (int l = 0; l < L; ++l) {
            const float wl = lds_c[l];
            const float4 v = e4[l * 256 + tid];
            a4.x += wl * v.x; a4.y += wl * v.y; a4.z += wl * v.z; a4.w += wl * v.w;
        }
        __syncthreads();
        reinterpret_cast<float4*>(lds_b)[tid] = a4;
        __syncthreads();
        const int r = b * 4 + wid;   // 1024 rows over blocks 0..255
        float acc = wsum(dot1024(comb_W + (size_t)r * (2 * H) + H, lds_b, lane));
        if (lane == 0)
            gput(ws + OFF_X + r, fmaxf(acc + gget(ws + OFF_CP + r) + comb_b[r], 0.f));
    }
    gbar(bar, 1);

    // ===== S3: gi (3 rows/wave) + gates -> h_new ============================
    if (b < 256) {
        for (int i = tid; i < H; i += NT) lds_a[i] = gget(ws + OFF_X + i);
        __syncthreads();
        const int t = b * 4 + wid;
        const float g0 = wsum(dot1024(w_ih + (size_t)t * H, lds_a, lane));
        const float g1 = wsum(dot1024(w_ih + (size_t)(H + t) * H, lds_a, lane));
        const float g2 = wsum(dot1024(w_ih + (size_t)(2 * H + t) * H, lds_a, lane));
        if (lane == 0) {
            const float ir = g0 + b_ih[t];
            const float iz = g1 + b_ih[H + t];
            const float in_ = g2 + b_ih[2 * H + t];
            const float hr = gget(ws + OFF_GH + t);
            const float hz = gget(ws + OFF_GH + H + t);
            const float hn = gget(ws + OFF_GH + 2 * H + t);
            const float r = 1.f / (1.f + expf(-(ir + hr)));
            const float z = 1.f / (1.f + expf(-(iz + hz)));
            const float n = tanhf(in_ + r * hn);
            const float hnew = (1.f - z) * n + z * hid[t];
            out[V + t] = hnew;                 // host-visible
            gput(ws + OFF_HN + t, hnew);       // device-coherent copy
        }
    }
    gbar(bar, 2);

    // ===== S4: out-proj GEMV, contiguous 50-row chunk per block ============
    for (int i = tid; i < H; i += NT) lds_a[i] = gget(ws + OFF_HN + i);
    __syncthreads();
    const int row0  = b * RPB;
    const int nrows = max(0, min(RPB, V - row0));
    for (int k = wid; k < nrows; k += 4) {
        const int r = row0 + k;
        float acc = wsum(dot1024(out_W + (size_t)r * H, lds_a, lane));
        if (lane == 0) lds_log[k] = acc + out_b[r];
    }
    __syncthreads();
    if (wid == 0) {  // wave 0: block (m,s) partial (nrows <= 50 < 64)
        const float v = (lane < nrows) ? lds_log[lane] : -INFINITY;
        const float m = wmax(v);
        const float e = (lane < nrows) ? expf(v - m) : 0.f;
        const float s = wsum(e);
        if (lane == 0) {
            gput(ws + OFF_PAIR + 2 * b, m);
            gput(ws + OFF_PAIR + 2 * b + 1, s);
        }
    }
    gbar(bar, 3);

    // ===== S5: redundant global LSE + final write ===========================
    float m = -INFINITY, s = 0.f;
    for (int i = tid; i < NB; i += NT) {
        const float mi = gget(ws + OFF_PAIR + 2 * i);
        const float si = gget(ws + OFF_PAIR + 2 * i + 1);
        if (si > 0.f) msmerge(m, s, mi, si);
    }
#pragma unroll
    for (int off = 32; off > 0; off >>= 1) {
        const float mo = __shfl_xor(m, off);
        const float so = __shfl_xor(s, off);
        if (so > 0.f) msmerge(m, s, mo, so);
    }
    if (lane == 0) { lds_c[wid] = m; lds_c[4 + wid] = s; }
    __syncthreads();
    if (tid == 0) {
        float M = lds_c[0], S = lds_c[4];
        for (int i = 1; i < 4; ++i)
            if (lds_c[4 + i] > 0.f) msmerge(M, S, lds_c[i], lds_c[4 + i]);
        lds_c[8] = M;
        lds_c[9] = logf(S);
    }
    __syncthreads();
    const float MM = lds_c[8], LS = lds_c[9];
    if (tid < nrows) out[row0 + tid] = lds_log[tid] - MM - LS;
}

extern "C" void kernel_launch(void* const* d_in, const int* in_sizes, int n_in,
                              void* d_out, int out_size, void* d_ws, size_t ws_size,
                              hipStream_t stream) {
    const long long* idx  = (const long long*)d_in[0];
    const float* hid    = (const float*)d_in[1];
    const float* enc    = (const float*)d_in[2];
    const float* emb    = (const float*)d_in[3];
    const float* attn_W = (const float*)d_in[4];
    const float* attn_b = (const float*)d_in[5];
    const float* comb_W = (const float*)d_in[6];
    const float* comb_b = (const float*)d_in[7];
    const float* w_ih   = (const float*)d_in[8];
    const float* w_hh   = (const float*)d_in[9];
    const float* b_ih   = (const float*)d_in[10];
    const float* b_hh   = (const float*)d_in[11];
    const float* out_W  = (const float*)d_in[12];
    const float* out_b  = (const float*)d_in[13];
    float* out = (float*)d_out;
    float* ws  = (float*)d_ws;

    hipMemsetAsync(d_ws, 0, BAR_UINTS * sizeof(unsigned), stream);
    mega<<<NB, NT, 0, stream>>>(idx, hid, enc, emb, attn_W, attn_b,
                                comb_W, comb_b, w_ih, w_hh, b_ih, b_hh,
                                out_W, out_b, ws, out);
}